// Round 1
// baseline (496.400 us; speedup 1.0000x reference)
//
#include <hip/hip_runtime.h>

#define DCH 64
#define BN_EPS 1e-5f

// ---------------------------------------------------------------------------
// K1: y = x @ W^T.  Block 256 threads handles 128 rows. W kept transposed in
// LDS (wt[k][o]); x tile staged with stride 68 (16B-aligned pad, conflict-free
// broadcast reads). Each thread computes 4 rows x 8 channels.
// ---------------------------------------------------------------------------
__global__ __launch_bounds__(256) void gemm_xwt(const float* __restrict__ x,
                                                const float* __restrict__ W,
                                                float* __restrict__ y, int N) {
    __shared__ float xs[128 * 68];
    __shared__ float wt[64 * 64];
    const int tid = threadIdx.x;
    const int blockRow = blockIdx.x * 128;

    // W transpose into LDS: wt[k*64+o] = W[o*64+k]
#pragma unroll
    for (int jj = 0; jj < 4; ++jj) {
        int idx4 = tid * 16 + jj * 4;
        int o = idx4 >> 6, k = idx4 & 63;
        float4 w4 = *(const float4*)&W[idx4];
        wt[(k + 0) * 64 + o] = w4.x;
        wt[(k + 1) * 64 + o] = w4.y;
        wt[(k + 2) * 64 + o] = w4.z;
        wt[(k + 3) * 64 + o] = w4.w;
    }
    // x tile: 128 rows x 64 ch = 2048 float4, coalesced
#pragma unroll
    for (int jj = 0; jj < 8; ++jj) {
        int f4 = tid + 256 * jj;           // 0..2047
        int rl = f4 >> 4, k4 = (f4 & 15) * 4;
        int row = blockRow + rl;
        float4 v = make_float4(0.f, 0.f, 0.f, 0.f);
        if (row < N) v = *(const float4*)&x[row * DCH + k4];
        *(float4*)&xs[rl * 68 + k4] = v;
    }
    __syncthreads();

    const int tc = tid & 7;   // channel group 0..7
    const int tr = tid >> 3;  // 0..31
    const int dc = tc * 8;
    float acc[4][8];
#pragma unroll
    for (int i = 0; i < 4; ++i)
#pragma unroll
        for (int j = 0; j < 8; ++j) acc[i][j] = 0.f;

#pragma unroll 4
    for (int k = 0; k < 64; ++k) {
        float4 w0 = *(const float4*)&wt[k * 64 + dc];
        float4 w1 = *(const float4*)&wt[k * 64 + dc + 4];
#pragma unroll
        for (int i = 0; i < 4; ++i) {
            float xv = xs[(tr + 32 * i) * 68 + k];
            acc[i][0] = fmaf(xv, w0.x, acc[i][0]);
            acc[i][1] = fmaf(xv, w0.y, acc[i][1]);
            acc[i][2] = fmaf(xv, w0.z, acc[i][2]);
            acc[i][3] = fmaf(xv, w0.w, acc[i][3]);
            acc[i][4] = fmaf(xv, w1.x, acc[i][4]);
            acc[i][5] = fmaf(xv, w1.y, acc[i][5]);
            acc[i][6] = fmaf(xv, w1.z, acc[i][6]);
            acc[i][7] = fmaf(xv, w1.w, acc[i][7]);
        }
    }
#pragma unroll
    for (int i = 0; i < 4; ++i) {
        int row = blockRow + tr + 32 * i;
        if (row < N) {
            *(float4*)&y[row * DCH + dc] =
                make_float4(acc[i][0], acc[i][1], acc[i][2], acc[i][3]);
            *(float4*)&y[row * DCH + dc + 4] =
                make_float4(acc[i][4], acc[i][5], acc[i][6], acc[i][7]);
        }
    }
}

// ---------------------------------------------------------------------------
// K2: acc[row] += val * y[col]  (edge-parallel, coalesced over the 64 channels)
// Each wave owns 64 edges; metadata broadcast via readlane (__shfl const lane).
// ---------------------------------------------------------------------------
__global__ __launch_bounds__(256) void spmm_atomic(const float* __restrict__ y,
                                                   const float* __restrict__ val,
                                                   const int* __restrict__ rows,
                                                   const int* __restrict__ cols,
                                                   float* __restrict__ acc, int E) {
    const int lane = threadIdx.x & 63;
    const int wave = threadIdx.x >> 6;
    const int e = (blockIdx.x * 4 + wave) * 64 + lane;
    float v = 0.f;
    int r = 0, c = 0;
    if (e < E) { v = val[e]; r = rows[e]; c = cols[e]; }
#pragma unroll
    for (int j = 0; j < 64; ++j) {
        int rj = __shfl(r, j);
        int cj = __shfl(c, j);
        float vj = __shfl(v, j);
        float yv = y[cj * DCH + lane];
        atomicAdd(&acc[rj * DCH + lane], vj * yv);
    }
}

// ---------------------------------------------------------------------------
// K3: in-place z = acc + b + x on d_out, accumulate per-channel sum / sumsq.
// channel = tid&63 is loop-invariant (stride multiple of 64).
// ---------------------------------------------------------------------------
__global__ __launch_bounds__(256) void resid_stats(float* __restrict__ zio,
                                                   const float* __restrict__ x,
                                                   const float* __restrict__ b,
                                                   float* __restrict__ stats,
                                                   int ND) {
    const int tid = threadIdx.x;
    const int d = tid & 63;
    const float bias = b[d];
    float s = 0.f, s2 = 0.f;
    const int stride = gridDim.x * 256;
    for (int i = blockIdx.x * 256 + tid; i < ND; i += stride) {
        float z = zio[i] + bias + x[i];
        zio[i] = z;
        s += z;
        s2 += z * z;
    }
    __shared__ float rs[4][64];
    __shared__ float rs2[4][64];
    const int wv = tid >> 6;
    rs[wv][d] = s;
    rs2[wv][d] = s2;
    __syncthreads();
    if (tid < 64) {
        float ts = rs[0][tid] + rs[1][tid] + rs[2][tid] + rs[3][tid];
        float ts2 = rs2[0][tid] + rs2[1][tid] + rs2[2][tid] + rs2[3][tid];
        atomicAdd(&stats[tid], ts);
        atomicAdd(&stats[64 + tid], ts2);
    }
}

// ---------------------------------------------------------------------------
// K4: BatchNorm (biased var) + ReLU in place.
// ---------------------------------------------------------------------------
__global__ __launch_bounds__(256) void bn_relu(float* __restrict__ out,
                                               const float* __restrict__ stats,
                                               const float* __restrict__ gamma,
                                               const float* __restrict__ beta,
                                               int ND, float invN) {
    const int tid = threadIdx.x;
    const int d = tid & 63;
    const float mean = stats[d] * invN;
    const float var = stats[64 + d] * invN - mean * mean;
    const float sc = gamma[d] * rsqrtf(var + BN_EPS);
    const float sh = beta[d] - mean * sc;
    const int stride = gridDim.x * 256;
    for (int i = blockIdx.x * 256 + tid; i < ND; i += stride) {
        out[i] = fmaxf(fmaf(out[i], sc, sh), 0.f);
    }
}

extern "C" void kernel_launch(void* const* d_in, const int* in_sizes, int n_in,
                              void* d_out, int out_size, void* d_ws, size_t ws_size,
                              hipStream_t stream) {
    const float* x       = (const float*)d_in[0];
    const float* adj_val = (const float*)d_in[1];
    const float* W       = (const float*)d_in[2];
    const float* b       = (const float*)d_in[3];
    const float* gamma   = (const float*)d_in[4];
    const float* beta    = (const float*)d_in[5];
    const int*   adj_row = (const int*)d_in[6];
    const int*   adj_col = (const int*)d_in[7];
    float* out = (float*)d_out;

    const int N  = in_sizes[0] / DCH;
    const int E  = in_sizes[1];
    const int ND = N * DCH;

    float* stats = (float*)d_ws;                      // 128 floats
    float* y     = (float*)((char*)d_ws + 4096);      // N*D floats

    (void)hipMemsetAsync(out, 0, (size_t)ND * sizeof(float), stream);
    (void)hipMemsetAsync(stats, 0, 128 * sizeof(float), stream);

    gemm_xwt<<<(N + 127) / 128, 256, 0, stream>>>(x, W, y, N);
    spmm_atomic<<<(E + 255) / 256, 256, 0, stream>>>(y, adj_val, adj_row, adj_col, out, E);
    resid_stats<<<1024, 256, 0, stream>>>(out, x, b, stats, ND);
    bn_relu<<<1024, 256, 0, stream>>>(out, stats, gamma, beta, ND, 1.0f / (float)N);
}

// Round 2
// 417.503 us; speedup vs baseline: 1.1890x; 1.1890x over previous
//
#include <hip/hip_runtime.h>

#define DCH 64
#define BN_EPS 1e-5f
#define SCAN_ELEMS 2048   // per block: 256 threads x 8

// ---------------------------------------------------------------------------
// K1: y = x @ W^T.  Block 256 threads handles 128 rows. W kept transposed in
// LDS; x tile staged with stride 68. Each thread: 4 rows x 8 channels.
// ---------------------------------------------------------------------------
__global__ __launch_bounds__(256) void gemm_xwt(const float* __restrict__ x,
                                                const float* __restrict__ W,
                                                float* __restrict__ y, int N) {
    __shared__ float xs[128 * 68];
    __shared__ float wt[64 * 64];
    const int tid = threadIdx.x;
    const int blockRow = blockIdx.x * 128;

#pragma unroll
    for (int jj = 0; jj < 4; ++jj) {
        int idx4 = tid * 16 + jj * 4;
        int o = idx4 >> 6, k = idx4 & 63;
        float4 w4 = *(const float4*)&W[idx4];
        wt[(k + 0) * 64 + o] = w4.x;
        wt[(k + 1) * 64 + o] = w4.y;
        wt[(k + 2) * 64 + o] = w4.z;
        wt[(k + 3) * 64 + o] = w4.w;
    }
#pragma unroll
    for (int jj = 0; jj < 8; ++jj) {
        int f4 = tid + 256 * jj;
        int rl = f4 >> 4, k4 = (f4 & 15) * 4;
        int row = blockRow + rl;
        float4 v = make_float4(0.f, 0.f, 0.f, 0.f);
        if (row < N) v = *(const float4*)&x[row * DCH + k4];
        *(float4*)&xs[rl * 68 + k4] = v;
    }
    __syncthreads();

    const int tc = tid & 7;
    const int tr = tid >> 3;
    const int dc = tc * 8;
    float acc[4][8];
#pragma unroll
    for (int i = 0; i < 4; ++i)
#pragma unroll
        for (int j = 0; j < 8; ++j) acc[i][j] = 0.f;

#pragma unroll 4
    for (int k = 0; k < 64; ++k) {
        float4 w0 = *(const float4*)&wt[k * 64 + dc];
        float4 w1 = *(const float4*)&wt[k * 64 + dc + 4];
#pragma unroll
        for (int i = 0; i < 4; ++i) {
            float xv = xs[(tr + 32 * i) * 68 + k];
            acc[i][0] = fmaf(xv, w0.x, acc[i][0]);
            acc[i][1] = fmaf(xv, w0.y, acc[i][1]);
            acc[i][2] = fmaf(xv, w0.z, acc[i][2]);
            acc[i][3] = fmaf(xv, w0.w, acc[i][3]);
            acc[i][4] = fmaf(xv, w1.x, acc[i][4]);
            acc[i][5] = fmaf(xv, w1.y, acc[i][5]);
            acc[i][6] = fmaf(xv, w1.z, acc[i][6]);
            acc[i][7] = fmaf(xv, w1.w, acc[i][7]);
        }
    }
#pragma unroll
    for (int i = 0; i < 4; ++i) {
        int row = blockRow + tr + 32 * i;
        if (row < N) {
            *(float4*)&y[row * DCH + dc] =
                make_float4(acc[i][0], acc[i][1], acc[i][2], acc[i][3]);
            *(float4*)&y[row * DCH + dc + 4] =
                make_float4(acc[i][4], acc[i][5], acc[i][6], acc[i][7]);
        }
    }
}

// --------------------------- CSR build ------------------------------------
__global__ __launch_bounds__(256) void hist_rows(const int* __restrict__ rows,
                                                 int* __restrict__ count, int E) {
    int e = blockIdx.x * 256 + threadIdx.x;
    if (e < E) atomicAdd(&count[rows[e]], 1);
}

// p1: per-block sums of count[] (SCAN_ELEMS per block)
__global__ __launch_bounds__(256) void scan_p1(const int* __restrict__ count,
                                               int* __restrict__ blocksum, int N) {
    __shared__ int sdata[256];
    const int tid = threadIdx.x;
    const int base = blockIdx.x * SCAN_ELEMS + tid * 8;
    int s = 0;
#pragma unroll
    for (int j = 0; j < 8; ++j) {
        int i = base + j;
        if (i < N) s += count[i];
    }
    sdata[tid] = s;
    __syncthreads();
    for (int off = 128; off > 0; off >>= 1) {
        if (tid < off) sdata[tid] += sdata[tid + off];
        __syncthreads();
    }
    if (tid == 0) blocksum[blockIdx.x] = sdata[0];
}

// p2: serial exclusive scan of blocksums (nb ~ 49), in place; rowptr[N]=total
__global__ void scan_p2(int* __restrict__ blocksum, int* __restrict__ rowptr,
                        int nb, int N) {
    if (threadIdx.x == 0 && blockIdx.x == 0) {
        int run = 0;
        for (int b = 0; b < nb; ++b) {
            int t = blocksum[b];
            blocksum[b] = run;
            run += t;
        }
        rowptr[N] = run;
    }
}

// p3: in-block exclusive scan + block offset -> rowptr[i], cursor[i]
__global__ __launch_bounds__(256) void scan_p3(const int* __restrict__ count,
                                               const int* __restrict__ blocksum,
                                               int* __restrict__ rowptr,
                                               int* __restrict__ cursor, int N) {
    __shared__ int sdata[256];
    const int tid = threadIdx.x;
    const int base = blockIdx.x * SCAN_ELEMS + tid * 8;
    int v[8];
    int tsum = 0;
#pragma unroll
    for (int j = 0; j < 8; ++j) {
        int i = base + j;
        v[j] = (i < N) ? count[i] : 0;
        tsum += v[j];
    }
    sdata[tid] = tsum;
    __syncthreads();
    // Hillis-Steele inclusive scan over 256 thread sums
    for (int off = 1; off < 256; off <<= 1) {
        int mine = sdata[tid];
        int add = (tid >= off) ? sdata[tid - off] : 0;
        __syncthreads();
        sdata[tid] = mine + add;
        __syncthreads();
    }
    int run = blocksum[blockIdx.x] + sdata[tid] - tsum;  // exclusive
#pragma unroll
    for (int j = 0; j < 8; ++j) {
        int i = base + j;
        if (i < N) {
            rowptr[i] = run;
            cursor[i] = run;
            run += v[j];
        }
    }
}

__global__ __launch_bounds__(256) void scatter_edges(const int* __restrict__ rows,
                                                     const int* __restrict__ cols,
                                                     const float* __restrict__ vals,
                                                     int* __restrict__ cursor,
                                                     int* __restrict__ col_s,
                                                     float* __restrict__ val_s, int E) {
    int e = blockIdx.x * 256 + threadIdx.x;
    if (e < E) {
        int r = rows[e];
        int pos = atomicAdd(&cursor[r], 1);
        col_s[pos] = cols[e];
        val_s[pos] = vals[e];
    }
}

// ---------------------------------------------------------------------------
// K2 fused: per-row SpMM (CSR) + bias + residual + stats.
// One wave per 8 rows; lane = channel. Writes z to out, per-channel
// sum/sumsq reduced in LDS, one atomic per channel per block (3125 blocks).
// ---------------------------------------------------------------------------
#define ROWS_PER_WAVE 8
__global__ __launch_bounds__(256) void spmm_fused(const float* __restrict__ y,
                                                  const int* __restrict__ rowptr,
                                                  const int* __restrict__ col_s,
                                                  const float* __restrict__ val_s,
                                                  const float* __restrict__ x,
                                                  const float* __restrict__ b,
                                                  float* __restrict__ out,
                                                  float* __restrict__ stats, int N) {
    const int lane = threadIdx.x & 63;
    const int wave = threadIdx.x >> 6;
    const int rbase = (blockIdx.x * 4 + wave) * ROWS_PER_WAVE;
    const float bias = b[lane];
    float s = 0.f, s2 = 0.f;
#pragma unroll
    for (int rr = 0; rr < ROWS_PER_WAVE; ++rr) {
        int r = rbase + rr;
        if (r >= N) break;
        int beg = rowptr[r], end = rowptr[r + 1];
        float acc = 0.f;
        int j = beg;
        for (; j + 3 < end; j += 4) {
            int c0 = col_s[j], c1 = col_s[j + 1], c2 = col_s[j + 2], c3 = col_s[j + 3];
            float v0 = val_s[j], v1 = val_s[j + 1], v2 = val_s[j + 2], v3 = val_s[j + 3];
            float y0 = y[c0 * DCH + lane];
            float y1 = y[c1 * DCH + lane];
            float y2 = y[c2 * DCH + lane];
            float y3 = y[c3 * DCH + lane];
            acc = fmaf(v0, y0, acc);
            acc = fmaf(v1, y1, acc);
            acc = fmaf(v2, y2, acc);
            acc = fmaf(v3, y3, acc);
        }
        for (; j < end; ++j) acc = fmaf(val_s[j], y[col_s[j] * DCH + lane], acc);
        float z = acc + bias + x[r * DCH + lane];
        out[r * DCH + lane] = z;
        s += z;
        s2 += z * z;
    }
    __shared__ float rs[4][64];
    __shared__ float rs2[4][64];
    rs[wave][lane] = s;
    rs2[wave][lane] = s2;
    __syncthreads();
    const int tid = threadIdx.x;
    if (tid < 64) {
        float ts = rs[0][tid] + rs[1][tid] + rs[2][tid] + rs[3][tid];
        float ts2 = rs2[0][tid] + rs2[1][tid] + rs2[2][tid] + rs2[3][tid];
        atomicAdd(&stats[tid], ts);
        atomicAdd(&stats[64 + tid], ts2);
    }
}

// ---------------------------------------------------------------------------
// K3: BatchNorm (biased var) + ReLU in place.
// ---------------------------------------------------------------------------
__global__ __launch_bounds__(256) void bn_relu(float* __restrict__ out,
                                               const float* __restrict__ stats,
                                               const float* __restrict__ gamma,
                                               const float* __restrict__ beta,
                                               int ND, float invN) {
    const int tid = threadIdx.x;
    const int d = tid & 63;
    const float mean = stats[d] * invN;
    const float var = stats[64 + d] * invN - mean * mean;
    const float sc = gamma[d] * rsqrtf(var + BN_EPS);
    const float sh = beta[d] - mean * sc;
    const int stride = gridDim.x * 256;
    for (int i = blockIdx.x * 256 + tid; i < ND; i += stride) {
        out[i] = fmaxf(fmaf(out[i], sc, sh), 0.f);
    }
}

extern "C" void kernel_launch(void* const* d_in, const int* in_sizes, int n_in,
                              void* d_out, int out_size, void* d_ws, size_t ws_size,
                              hipStream_t stream) {
    const float* x       = (const float*)d_in[0];
    const float* adj_val = (const float*)d_in[1];
    const float* W       = (const float*)d_in[2];
    const float* b       = (const float*)d_in[3];
    const float* gamma   = (const float*)d_in[4];
    const float* beta    = (const float*)d_in[5];
    const int*   adj_row = (const int*)d_in[6];
    const int*   adj_col = (const int*)d_in[7];
    float* out = (float*)d_out;

    const int N  = in_sizes[0] / DCH;
    const int E  = in_sizes[1];
    const int ND = N * DCH;
    const int nb = (N + SCAN_ELEMS - 1) / SCAN_ELEMS;

    // workspace layout (byte offsets), all 128B-aligned
    char* ws = (char*)d_ws;
    size_t off = 0;
    float* stats  = (float*)(ws + off); off += 4096;
    int* count    = (int*)(ws + off);   off += ((size_t)N * 4 + 127) & ~127ull;
    int* cursor   = (int*)(ws + off);   off += ((size_t)N * 4 + 127) & ~127ull;
    int* rowptr   = (int*)(ws + off);   off += ((size_t)(N + 1) * 4 + 127) & ~127ull;
    int* blocksum = (int*)(ws + off);   off += ((size_t)(nb + 1) * 4 + 127) & ~127ull;
    float* y      = (float*)(ws + off); off += (size_t)ND * 4;
    int* col_s    = (int*)(ws + off);   off += (size_t)E * 4;
    float* val_s  = (float*)(ws + off); off += (size_t)E * 4;

    // zero stats + count in one memset (they are adjacent at ws start)
    (void)hipMemsetAsync(ws, 0, 4096 + (size_t)N * 4, stream);

    gemm_xwt<<<(N + 127) / 128, 256, 0, stream>>>(x, W, y, N);
    hist_rows<<<(E + 255) / 256, 256, 0, stream>>>(adj_row, count, E);
    scan_p1<<<nb, 256, 0, stream>>>(count, blocksum, N);
    scan_p2<<<1, 64, 0, stream>>>(blocksum, rowptr, nb, N);
    scan_p3<<<nb, 256, 0, stream>>>(count, blocksum, rowptr, cursor, N);
    scatter_edges<<<(E + 255) / 256, 256, 0, stream>>>(adj_row, adj_col, adj_val,
                                                       cursor, col_s, val_s, E);
    spmm_fused<<<(N + 4 * ROWS_PER_WAVE - 1) / (4 * ROWS_PER_WAVE), 256, 0, stream>>>(
        y, rowptr, col_s, val_s, x, b, out, stats, N);
    bn_relu<<<1024, 256, 0, stream>>>(out, stats, gamma, beta, ND, 1.0f / (float)N);
}